// Round 14
// baseline (608.737 us; speedup 1.0000x reference)
//
#include <hip/hip_runtime.h>
#include <hip/hip_bf16.h>
#include <cstdint>
#include <cstddef>

#define N_TOK 8192
#define DIM   2048
#define HID   2048
#define NE    8
#define ARENA 18432   // 16384 + 8*256 max padded rows

typedef _Float16 half8  __attribute__((ext_vector_type(8)));
typedef _Float16 half4v __attribute__((ext_vector_type(4)));
typedef float    floatx4 __attribute__((ext_vector_type(4)));

#define BARR  __builtin_amdgcn_s_barrier()
#define LGKM0 asm volatile("s_waitcnt lgkmcnt(0)" ::: "memory")

__device__ inline void gload_lds16(const void* g, void* l) {
    __builtin_amdgcn_global_load_lds(
        (const __attribute__((address_space(1))) unsigned int*)g,
        (__attribute__((address_space(3))) unsigned int*)l, 16, 0, 0);
}

__device__ __forceinline__ floatx4 MF(half8 a, half8 b, floatx4 c) {
    return __builtin_amdgcn_mfma_f32_16x16x32_f16(a, b, c, 0, 0, 0);
}

// ========== merged prep (W transpose->fp16) + gate (logits/top2/x->fp16) ==========
__global__ __launch_bounds__(256) void k_prep_gate(
        const float* __restrict__ W1, const float* __restrict__ W2,
        _Float16* __restrict__ w1t, _Float16* __restrict__ w2t,
        const float* __restrict__ x, const float* __restrict__ Wg,
        const float* __restrict__ bg, _Float16* __restrict__ xh,
        int* __restrict__ te, float* __restrict__ tw, int* __restrict__ counts) {
    __shared__ __align__(16) char smem[65568];
    int b = blockIdx.x;
    if (b < 16384) {
        // ---------------- prep ----------------
        float (*tile)[65] = (float (*)[65])smem;
        int z = b >> 10, rem = b & 1023;
        int r0 = (rem >> 5) * 64, c0 = (rem & 31) * 64;
        const float* in = (z < 8) ? W1 : W2;
        _Float16* out   = (z < 8) ? w1t : w2t;
        int e  = z & 7;
        int tc = threadIdx.x & 63, tr = threadIdx.x >> 6;
        const float* ip = in + ((size_t)e * 2048 + r0) * 2048 + c0;
#pragma unroll
        for (int i = 0; i < 16; i++)
            tile[tr + i * 4][tc] = ip[(size_t)(tr + i * 4) * 2048 + tc];
        __syncthreads();
        _Float16* op = out + ((size_t)e * 2048 + c0) * 2048 + r0;
#pragma unroll
        for (int i = 0; i < 16; i++) {
            int cc = tr + i * 4;
            op[(size_t)cc * 2048 + tc] = (_Float16)tile[tc][cc];
        }
        return;
    }
    // ---------------- gate ----------------
    int bid = b - 16384;
    float* wgs = (float*)smem;             // 64 KB transposed [e][d]
    int* lcnt  = (int*)(smem + 65536);
    if (threadIdx.x < NE) lcnt[threadIdx.x] = 0;
    for (int i = threadIdx.x; i < NE * DIM; i += 256)
        wgs[(i & 7) * DIM + (i >> 3)] = Wg[i];
    __syncthreads();
    int wv = threadIdx.x >> 6, l = threadIdx.x & 63;
#pragma unroll 1
    for (int it = 0; it < 4; ++it) {
        int t = bid * 16 + wv * 4 + it;
        const float* xr = x + (size_t)t * DIM;
        double acc[NE] = {0, 0, 0, 0, 0, 0, 0, 0};
#pragma unroll 2
        for (int i = 0; i < 8; i++) {
            int d0 = i * 256 + l * 4;
            float4 xv = *(const float4*)(xr + d0);
            half4v hv;
            hv[0] = (_Float16)xv.x; hv[1] = (_Float16)xv.y;
            hv[2] = (_Float16)xv.z; hv[3] = (_Float16)xv.w;
            *(half4v*)(xh + (size_t)t * DIM + d0) = hv;
#pragma unroll
            for (int e = 0; e < NE; e++) {
                float4 w4 = *(const float4*)(wgs + e * DIM + d0);
                acc[e] += (double)xv.x * w4.x + (double)xv.y * w4.y +
                          (double)xv.z * w4.z + (double)xv.w * w4.w;
            }
        }
#pragma unroll
        for (int e = 0; e < NE; e++) {
            double v = acc[e];
            v += __shfl_xor(v, 32, 64); v += __shfl_xor(v, 16, 64);
            v += __shfl_xor(v, 8, 64);  v += __shfl_xor(v, 4, 64);
            v += __shfl_xor(v, 2, 64);  v += __shfl_xor(v, 1, 64);
            acc[e] = v;
        }
        if (l == 0) {
            double best0 = -1e300, best1 = -1e300; int i0 = 0, i1 = 0;
#pragma unroll
            for (int e = 0; e < NE; e++) {
                double lg = acc[e] + (double)bg[e];
                if (lg > best0) { best1 = best0; i1 = i0; best0 = lg; i0 = e; }
                else if (lg > best1) { best1 = lg; i1 = e; }
            }
            float d  = expf((float)(best1 - best0));
            float w0 = 1.f / (1.f + d), w1 = d / (1.f + d);
            te[2 * t] = i0; te[2 * t + 1] = i1;
            tw[2 * t] = w0; tw[2 * t + 1] = w1;
            atomicAdd(&lcnt[i0], 1);
            atomicAdd(&lcnt[i1], 1);
        }
    }
    __syncthreads();
    if (threadIdx.x < NE) atomicAdd(&counts[threadIdx.x], lcnt[threadIdx.x]);
}

// ---------------- scan: padded arena offsets + job table ----------------
__global__ void k_scan(const int* __restrict__ counts, int* __restrict__ fill,
                       int* __restrict__ poff, int* __restrict__ cj) {
    if (threadIdx.x == 0 && blockIdx.x == 0) {
        int a = 0, jc = 0;
        for (int e = 0; e < NE; e++) {
            poff[e] = a; cj[e] = jc;
            int mb = (counts[e] + 255) >> 8;
            a  += mb << 8;
            jc += mb * 16;       // 16 n-tiles of 128
            fill[e] = 0;
        }
        poff[NE] = a; cj[NE] = jc;
    }
}

// ---------------- scatter tokens to padded expert arena ----------------
__global__ __launch_bounds__(256) void k_scatter(const int* __restrict__ te,
                                                 const float* __restrict__ tw,
                                                 const int* __restrict__ poff,
                                                 int* __restrict__ fill,
                                                 int* __restrict__ ltok,
                                                 float* __restrict__ lw,
                                                 int* __restrict__ tslot) {
    int t = blockIdx.x * blockDim.x + threadIdx.x;
    if (t >= N_TOK) return;
#pragma unroll
    for (int k = 0; k < 2; k++) {
        int e = te[2 * t + k];
        int p = atomicAdd(&fill[e], 1);
        int idx = poff[e] + p;
        ltok[idx] = t; lw[idx] = tw[2 * t + k]; tslot[2 * t + k] = idx;
    }
}

// ====== GEMM: BM=256, BN=128, BK=32, DOUBLE-buffer, 2 blocks/CU ======
// 512 thr = 8 waves (4m x 2n); wave tile 64x64; acc[4][4] of 16x16x32_f16.
// LDS: As[2][256][32] + Bs[2][128][32] fp16 = 48 KB -> 2 blocks/CU (same as
// R10/R13's proven residency; unified VGPR ~124/wave caps at 4 waves/SIMD).
// New vs R13: double buffer + counted vmcnt(3) hides the staging latency that
// the single-buffer VMC0 exposed every tile.
// Per iter t (steady):   [in flight at entry: tile t's 3 loads]
//   stage t+1 -> buf[(t+1)&1]   (region's last readers = tile t-1, retired by
//                                iter t-1's LGKM0+BARR -> write-safe)
//   vmcnt(3)  (forces tile t's 3 loads, issued one full compute-tile ago ->
//              latency hidden; t+1's 3 stay in flight)
//   BARR      (all waves proved their own disjoint t-regions landed)
//   compute buf[t&1]: 8 ds_read_b128 + 16 MFMA (setprio-wrapped)
//   LGKM0; BARR  (all waves' reads retired -> next iter may overwrite)
// Bank balance: 64B row stride => wave read covers all (row,chunk) combos,
// 8 accesses/bank = wave minimum -> no swizzle needed at BK=32.

template<int LAYER>
__global__ __launch_bounds__(512, 4) void k_gemm(const _Float16* __restrict__ Ain,
                                                 const _Float16* __restrict__ Bt,
                                                 const float* __restrict__ bias,
                                                 const int* __restrict__ cj,
                                                 const int* __restrict__ poff,
                                                 const int* __restrict__ ltok,
                                                 const float* __restrict__ lw,
                                                 _Float16* __restrict__ Cout) {
    __shared__ _Float16 As[2 * 256 * 32];   // 32 KB
    __shared__ _Float16 Bs[2 * 128 * 32];   // 16 KB

    int j = blockIdx.x;
    if (j >= cj[NE]) return;
    int e = 0;
#pragma unroll
    for (int k = 0; k < NE - 1; k++) e += (j >= cj[k + 1]);
    int r  = j - cj[e];
    int m0 = poff[e] + (r >> 4) * 256;   // arena row base
    int n0 = (r & 15) * 128;

    int tid = threadIdx.x;
    int l = tid & 63;
    int wid = tid >> 6;
    int wm = wid >> 1, wn = wid & 1;     // 4m x 2n
    int lr = l & 15, lk = l >> 4;
    int rA = (wm * 64 + lr) * 32;        // halves
    int rB = (wn * 64 + lr) * 32;
    int cbo = lk * 8;                    // k-chunk (no swizzle at BK=32)

    // staging: A 2 loads/thread (rows tid>>2 + {0,128}), B 1 load (row tid>>2);
    // dest lane-linear tid*8 halves (m104-safe); src k-offset (tid&3)*8.
    int sd = tid * 8;
    size_t koff = (size_t)((tid & 3) * 8);

    const _Float16* aS[2];
#pragma unroll
    for (int q = 0; q < 2; q++) {
        int ar = m0 + (tid >> 2) + q * 128;
        if constexpr (LAYER == 1) {
            int tok = ltok[ar];
            aS[q] = Ain + (size_t)tok * DIM + koff;
        } else {
            aS[q] = Ain + (size_t)ar * HID + koff;
        }
    }
    const _Float16* bS = Bt + ((size_t)(e * 2048 + n0 + (tid >> 2))) * 2048 + koff;

    floatx4 acc[4][4];
#pragma unroll
    for (int m = 0; m < 4; m++)
#pragma unroll
        for (int n = 0; n < 4; n++) acc[m][n] = (floatx4){0.f, 0.f, 0.f, 0.f};

    // prologue: stage tile 0 -> buf0
    gload_lds16(aS[0], As + sd);
    gload_lds16(aS[1], As + 4096 + sd);
    gload_lds16(bS,    Bs + sd);

    const int NT = DIM / 32;   // 64
#pragma unroll 1
    for (int t = 0; t < NT; ++t) {
        if (t < NT - 1) {
            int bn = (t + 1) & 1;
            gload_lds16(aS[0] + (size_t)(t + 1) * 32, As + bn * 8192 + sd);
            gload_lds16(aS[1] + (size_t)(t + 1) * 32, As + bn * 8192 + 4096 + sd);
            gload_lds16(bS    + (size_t)(t + 1) * 32, Bs + bn * 4096 + sd);
            asm volatile("s_waitcnt vmcnt(3)" ::: "memory");  // tile t landed
        } else {
            asm volatile("s_waitcnt vmcnt(0)" ::: "memory");
        }
        BARR;
        const _Float16* Ab = As + (t & 1) * 8192;
        const _Float16* Bb = Bs + (t & 1) * 4096;
        half8 a[4], b[4];
#pragma unroll
        for (int fm = 0; fm < 4; fm++)
            a[fm] = *(const half8*)(Ab + rA + fm * 512 + cbo);
#pragma unroll
        for (int fn = 0; fn < 4; fn++)
            b[fn] = *(const half8*)(Bb + rB + fn * 512 + cbo);
        __builtin_amdgcn_s_setprio(1);
#pragma unroll
        for (int fn = 0; fn < 4; fn++)
#pragma unroll
            for (int fm = 0; fm < 4; fm++)
                acc[fm][fn] = MF(a[fm], b[fn], acc[fm][fn]);
        __builtin_amdgcn_s_setprio(0);
        LGKM0;   // own reads retired
        BARR;    // all waves done reading buf[t&1] -> next iter may overwrite
    }

    // epilogue (no row guards - arena is padded)
#pragma unroll
    for (int fm = 0; fm < 4; fm++) {
        int row0 = m0 + wm * 64 + fm * 16 + lk * 4;
#pragma unroll
        for (int fn = 0; fn < 4; fn++) {
            int col = n0 + wn * 64 + fn * 16 + lr;
            float bv = bias[e * 2048 + col];
#pragma unroll
            for (int rr = 0; rr < 4; rr++) {
                int row = row0 + rr;
                float v = acc[fm][fn][rr] + bv;
                if constexpr (LAYER == 1) {
                    v = v > 0.f ? v : 0.f;
                } else {
                    v *= lw[row];
                }
                Cout[(size_t)row * HID + col] = (_Float16)v;
            }
        }
    }
}

// ---------------- combine the two weighted expert rows per token ----------------
__global__ __launch_bounds__(256) void k_combine(const _Float16* __restrict__ yb,
                                                 const int* __restrict__ tslot,
                                                 float* __restrict__ out) {
    int t = blockIdx.x;
    int s0 = tslot[2 * t], s1 = tslot[2 * t + 1];
    int c = threadIdx.x * 8;
    half8 y0 = *(const half8*)&yb[(size_t)s0 * HID + c];
    half8 y1 = *(const half8*)&yb[(size_t)s1 * HID + c];
    float* op = out + (size_t)t * HID + c;
    float4 o;
    o.x = (float)y0[0] + (float)y1[0];
    o.y = (float)y0[1] + (float)y1[1];
    o.z = (float)y0[2] + (float)y1[2];
    o.w = (float)y0[3] + (float)y1[3];
    *(float4*)(op) = o;
    o.x = (float)y0[4] + (float)y1[4];
    o.y = (float)y0[5] + (float)y1[5];
    o.z = (float)y0[6] + (float)y1[6];
    o.w = (float)y0[7] + (float)y1[7];
    *(float4*)(op + 4) = o;
}

extern "C" void kernel_launch(void* const* d_in, const int* in_sizes, int n_in,
                              void* d_out, int out_size, void* d_ws, size_t ws_size,
                              hipStream_t stream) {
    const float* x  = (const float*)d_in[0];
    const float* Wg = (const float*)d_in[1];
    const float* bg = (const float*)d_in[2];
    const float* W1 = (const float*)d_in[3];
    const float* b1 = (const float*)d_in[4];
    const float* W2 = (const float*)d_in[5];
    const float* b2 = (const float*)d_in[6];
    float* out = (float*)d_out;

    // ws layout (yb aliases xh+w1t, both dead by gemm2)
    char* ws = (char*)d_ws;
    _Float16* xh  = (_Float16*)(ws);
    _Float16* yb  = (_Float16*)(ws);                        // alias: safe, see order
    _Float16* w1t = (_Float16*)(ws + 33554432ULL);
    _Float16* w2t = (_Float16*)(ws + 100663296ULL);
    _Float16* hb  = (_Float16*)(ws + 167772160ULL);
    char* rt = ws + 167772160ULL + (size_t)ARENA * HID * 2; // 243,269,632
    int*   counts = (int*)(rt);              // 8
    int*   fill   = (int*)(rt + 32);         // 8
    int*   poff   = (int*)(rt + 64);         // 9
    int*   cj     = (int*)(rt + 128);        // 9
    int*   te     = (int*)(rt + 192);        // 16384 ints
    float* tw     = (float*)(rt + 192 + 65536);
    int*   tslot  = (int*)(rt + 192 + 131072);
    int*   ltok   = (int*)(rt + 192 + 196608);              // ARENA ints
    float* lw     = (float*)(rt + 192 + 196608 + 73728);    // ARENA floats

    hipMemsetAsync(rt, 0, 64, stream);                   // counts + fill
    hipMemsetAsync(ltok, 0, (size_t)ARENA * 8, stream);  // ltok + lw pads = 0
    k_prep_gate<<<dim3(16896), 256, 0, stream>>>(W1, W2, w1t, w2t,
                                                 x, Wg, bg, xh, te, tw, counts);
    k_scan<<<1, 64, 0, stream>>>(counts, fill, poff, cj);
    k_scatter<<<32, 256, 0, stream>>>(te, tw, poff, fill, ltok, lw, tslot);
    k_gemm<1><<<dim3(1152), 512, 0, stream>>>(xh, w1t, b1, cj, poff, ltok, nullptr, hb);
    k_gemm<2><<<dim3(1152), 512, 0, stream>>>(hb, w2t, b2, cj, poff, ltok, lw, yb);
    k_combine<<<8192, 256, 0, stream>>>(yb, tslot, out);
}

// Round 15
// 463.390 us; speedup vs baseline: 1.3137x; 1.3137x over previous
//
#include <hip/hip_runtime.h>
#include <hip/hip_bf16.h>
#include <cstdint>
#include <cstddef>

#define N_TOK 8192
#define DIM   2048
#define HID   2048
#define NE    8
#define ARENA 18432   // 16384 + 8*256 max padded rows
#define NJOBS 1152    // >= sum_e ceil(cnt_e/256)*16 (worst case 72*16)

typedef _Float16 half8  __attribute__((ext_vector_type(8)));
typedef _Float16 half4v __attribute__((ext_vector_type(4)));
typedef float    floatx4 __attribute__((ext_vector_type(4)));

#define BARR  __builtin_amdgcn_s_barrier()
#define LGKM0 asm volatile("s_waitcnt lgkmcnt(0)" ::: "memory")
#define VMC0  asm volatile("s_waitcnt vmcnt(0)" ::: "memory")

__device__ inline void gload_lds16(const void* g, void* l) {
    __builtin_amdgcn_global_load_lds(
        (const __attribute__((address_space(1))) unsigned int*)g,
        (__attribute__((address_space(3))) unsigned int*)l, 16, 0, 0);
}

__device__ __forceinline__ floatx4 MF(half8 a, half8 b, floatx4 c) {
    return __builtin_amdgcn_mfma_f32_16x16x32_f16(a, b, c, 0, 0, 0);
}

// ========== merged prep(W1 transpose->fp16) + gate (logits/top2/x->fp16) ==========
// blocks [0,8192): transpose W1 [E][R][C] fp32 -> [E][C][R] fp16
// blocks [8192,8704): gate. prep is HBM-bound, gate latency-bound -> overlap.
// (W2's transpose is merged into the gemm1 dispatch - it is not a gemm1 dep.)
__global__ __launch_bounds__(256) void k_prep_gate(
        const float* __restrict__ W1, _Float16* __restrict__ w1t,
        const float* __restrict__ x, const float* __restrict__ Wg,
        const float* __restrict__ bg, _Float16* __restrict__ xh,
        int* __restrict__ te, float* __restrict__ tw, int* __restrict__ counts) {
    __shared__ __align__(16) char smem[65568];
    int b = blockIdx.x;
    if (b < 8192) {
        // ---------------- prep W1 ----------------
        float (*tile)[65] = (float (*)[65])smem;
        int e = b >> 10, rem = b & 1023;
        int r0 = (rem >> 5) * 64, c0 = (rem & 31) * 64;
        int tc = threadIdx.x & 63, tr = threadIdx.x >> 6;   // tr 0..3
        const float* ip = W1 + ((size_t)e * 2048 + r0) * 2048 + c0;
#pragma unroll
        for (int i = 0; i < 16; i++)
            tile[tr + i * 4][tc] = ip[(size_t)(tr + i * 4) * 2048 + tc];
        __syncthreads();
        _Float16* op = w1t + ((size_t)e * 2048 + c0) * 2048 + r0;
#pragma unroll
        for (int i = 0; i < 16; i++) {
            int cc = tr + i * 4;
            op[(size_t)cc * 2048 + tc] = (_Float16)tile[tc][cc];
        }
        return;
    }
    // ---------------- gate ----------------
    int bid = b - 8192;
    float* wgs = (float*)smem;             // 64 KB transposed [e][d]
    int* lcnt  = (int*)(smem + 65536);
    if (threadIdx.x < NE) lcnt[threadIdx.x] = 0;
    for (int i = threadIdx.x; i < NE * DIM; i += 256)
        wgs[(i & 7) * DIM + (i >> 3)] = Wg[i];
    __syncthreads();
    int wv = threadIdx.x >> 6, l = threadIdx.x & 63;
#pragma unroll 1
    for (int it = 0; it < 4; ++it) {
        int t = bid * 16 + wv * 4 + it;
        const float* xr = x + (size_t)t * DIM;
        double acc[NE] = {0, 0, 0, 0, 0, 0, 0, 0};
#pragma unroll 2
        for (int i = 0; i < 8; i++) {
            int d0 = i * 256 + l * 4;
            float4 xv = *(const float4*)(xr + d0);
            half4v hv;
            hv[0] = (_Float16)xv.x; hv[1] = (_Float16)xv.y;
            hv[2] = (_Float16)xv.z; hv[3] = (_Float16)xv.w;
            *(half4v*)(xh + (size_t)t * DIM + d0) = hv;
#pragma unroll
            for (int e = 0; e < NE; e++) {
                float4 w4 = *(const float4*)(wgs + e * DIM + d0);
                acc[e] += (double)xv.x * w4.x + (double)xv.y * w4.y +
                          (double)xv.z * w4.z + (double)xv.w * w4.w;
            }
        }
#pragma unroll
        for (int e = 0; e < NE; e++) {
            double v = acc[e];
            v += __shfl_xor(v, 32, 64); v += __shfl_xor(v, 16, 64);
            v += __shfl_xor(v, 8, 64);  v += __shfl_xor(v, 4, 64);
            v += __shfl_xor(v, 2, 64);  v += __shfl_xor(v, 1, 64);
            acc[e] = v;
        }
        if (l == 0) {
            double best0 = -1e300, best1 = -1e300; int i0 = 0, i1 = 0;
#pragma unroll
            for (int e = 0; e < NE; e++) {
                double lg = acc[e] + (double)bg[e];
                if (lg > best0) { best1 = best0; i1 = i0; best0 = lg; i0 = e; }
                else if (lg > best1) { best1 = lg; i1 = e; }
            }
            float d  = expf((float)(best1 - best0));
            float w0 = 1.f / (1.f + d), w1 = d / (1.f + d);
            te[2 * t] = i0; te[2 * t + 1] = i1;
            tw[2 * t] = w0; tw[2 * t + 1] = w1;
            atomicAdd(&lcnt[i0], 1);
            atomicAdd(&lcnt[i1], 1);
        }
    }
    __syncthreads();
    if (threadIdx.x < NE) atomicAdd(&counts[threadIdx.x], lcnt[threadIdx.x]);
}

// ---------------- route: scan (padded arena offsets + job table) + scatter ----------------
__global__ __launch_bounds__(256) void k_route(const int* __restrict__ counts,
                                               int* __restrict__ poff, int* __restrict__ cj,
                                               const int* __restrict__ te,
                                               const float* __restrict__ tw,
                                               int* __restrict__ ltok, float* __restrict__ lw,
                                               int* __restrict__ tslot) {
    __shared__ int spoff[NE], sfill[NE];
    if (threadIdx.x == 0) {
        int a = 0, jc = 0;
        for (int e = 0; e < NE; e++) {
            poff[e] = a; cj[e] = jc; spoff[e] = a;
            int mb = (counts[e] + 255) >> 8;
            a  += mb << 8;
            jc += mb * 16;       // 16 n-tiles of 128
        }
        poff[NE] = a; cj[NE] = jc;
    }
    if (threadIdx.x < NE) sfill[threadIdx.x] = 0;
    __syncthreads();
#pragma unroll 1
    for (int t = threadIdx.x; t < N_TOK; t += 256) {
#pragma unroll
        for (int k = 0; k < 2; k++) {
            int e = te[2 * t + k];
            int p = atomicAdd(&sfill[e], 1);
            int idx = spoff[e] + p;
            ltok[idx] = t; lw[idx] = tw[2 * t + k]; tslot[2 * t + k] = idx;
        }
    }
}

// ====== m97-style GEMM: BM=256, BN=128, BK=64, single-buffer, 2 blocks/CU ======
// 512 thr = 8 waves (4m x 2n); wave tile 64x64; acc[4][4] of 16x16x32_f16.
// LDS 48 KB single buffer; __launch_bounds__(512,4): 2 blocks/CU (proven R10/R13;
// (512,6) spills - R11; atomic epilogue - R12; BK=32 dbuf - R14: all regressed).
// Co-resident blocks fill each other's drain/barrier stalls (m114).
// XOR swizzle both-sides (rule 21): physical 16B chunk = logical ^ (row&7).
// LAYER==1 extra: blocks [NJOBS, NJOBS+8192) transpose W2 (fp32->fp16 [E][C][R])
// - gemm1 is compute-bound (24% HBM), so W2 prep hides under it and fills the
// job-quantization tail (transpose blocks dispatch after gemm jobs).

template<int LAYER>
__global__ __launch_bounds__(512, 4) void k_gemm(const _Float16* __restrict__ Ain,
                                                 const _Float16* __restrict__ Bt,
                                                 const float* __restrict__ bias,
                                                 const int* __restrict__ cj,
                                                 const int* __restrict__ poff,
                                                 const int* __restrict__ ltok,
                                                 const float* __restrict__ lw,
                                                 const float* __restrict__ W2in,
                                                 _Float16* __restrict__ w2tO,
                                                 _Float16* __restrict__ Cout) {
    __shared__ __align__(16) char smem[49152];
    int j = blockIdx.x;

    if constexpr (LAYER == 1) {
        if (j >= NJOBS) {
            // ---------------- W2 transpose (512 threads) ----------------
            float (*tile)[65] = (float (*)[65])smem;      // 16.6 KB of the 48
            int b2 = j - NJOBS;
            int e = b2 >> 10, rem = b2 & 1023;
            int r0 = (rem >> 5) * 64, c0 = (rem & 31) * 64;
            int tc = threadIdx.x & 63, tr = threadIdx.x >> 6;   // tr 0..7
            const float* ip = W2in + ((size_t)e * 2048 + r0) * 2048 + c0;
#pragma unroll
            for (int i = 0; i < 8; i++)
                tile[tr + i * 8][tc] = ip[(size_t)(tr + i * 8) * 2048 + tc];
            __syncthreads();
            _Float16* op = w2tO + ((size_t)e * 2048 + c0) * 2048 + r0;
#pragma unroll
            for (int i = 0; i < 8; i++) {
                int cc = tr + i * 8;
                op[(size_t)cc * 2048 + tc] = (_Float16)tile[tc][cc];
            }
            return;
        }
    }

    _Float16* As = (_Float16*)smem;             // 256x64 halves = 32 KB
    _Float16* Bs = (_Float16*)(smem + 32768);   // 128x64 halves = 16 KB

    if (j >= cj[NE]) return;
    int e = 0;
#pragma unroll
    for (int k = 0; k < NE - 1; k++) e += (j >= cj[k + 1]);
    int r  = j - cj[e];
    int m0 = poff[e] + (r >> 4) * 256;   // arena row base
    int n0 = (r & 15) * 128;

    int tid = threadIdx.x;
    int l = tid & 63;
    int wid = tid >> 6;
    int wm = wid >> 1, wn = wid & 1;     // 4m x 2n
    int lr = l & 15, lk = l >> 4;
    int rA = (wm * 64 + lr) * 64;
    int rB = (wn * 64 + lr) * 64;

    int sd = tid * 8;                    // staging dest (lane-linear, m104-safe)
    size_t koff = (size_t)(((tid & 7) ^ ((tid >> 3) & 7)) * 8);  // pre-swizzled

    const _Float16* aS[4];
#pragma unroll
    for (int q = 0; q < 4; q++) {
        int ar = m0 + (tid >> 3) + q * 64;
        if constexpr (LAYER == 1) {
            int tok = ltok[ar];
            aS[q] = Ain + (size_t)tok * DIM + koff;
        } else {
            aS[q] = Ain + (size_t)ar * HID + koff;
        }
    }
    const _Float16* bS[2];
#pragma unroll
    for (int q = 0; q < 2; q++)
        bS[q] = Bt + ((size_t)(e * 2048 + n0 + (tid >> 3) + q * 64)) * 2048 + koff;

    floatx4 acc[4][4];
#pragma unroll
    for (int m = 0; m < 4; m++)
#pragma unroll
        for (int n = 0; n < 4; n++) acc[m][n] = (floatx4){0.f, 0.f, 0.f, 0.f};

    // prologue: stage tile 0
#pragma unroll
    for (int q = 0; q < 4; q++) gload_lds16(aS[q], As + sd + q * 4096);
#pragma unroll
    for (int q = 0; q < 2; q++) gload_lds16(bS[q], Bs + sd + q * 4096);

#pragma unroll 1
    for (int t = 0; t < 32; ++t) {
        VMC0;    // staged tile t landed (co-resident block covers this drain)
        BARR;
#pragma unroll
        for (int kk = 0; kk < 2; kk++) {
            int cbo = ((kk * 4 + lk) ^ (lr & 7)) * 8;
            half8 a[4], b[4];
#pragma unroll
            for (int fm = 0; fm < 4; fm++)
                a[fm] = *(const half8*)(As + rA + fm * 1024 + cbo);
#pragma unroll
            for (int fn = 0; fn < 4; fn++)
                b[fn] = *(const half8*)(Bs + rB + fn * 1024 + cbo);
#pragma unroll
            for (int fn = 0; fn < 4; fn++)
#pragma unroll
                for (int fm = 0; fm < 4; fm++)
                    acc[fm][fn] = MF(a[fm], b[fn], acc[fm][fn]);
        }
        LGKM0;   // own reads retired
        BARR;    // all waves done reading -> safe to overwrite buffer
        if (t < 31) {
#pragma unroll
            for (int q = 0; q < 4; q++)
                gload_lds16(aS[q] + (size_t)(t + 1) * 64, As + sd + q * 4096);
#pragma unroll
            for (int q = 0; q < 2; q++)
                gload_lds16(bS[q] + (size_t)(t + 1) * 64, Bs + sd + q * 4096);
        }
    }

    // epilogue (no row guards - arena is padded)
#pragma unroll
    for (int fm = 0; fm < 4; fm++) {
        int row0 = m0 + wm * 64 + fm * 16 + lk * 4;
#pragma unroll
        for (int fn = 0; fn < 4; fn++) {
            int col = n0 + wn * 64 + fn * 16 + lr;
            float bv = bias[e * 2048 + col];
#pragma unroll
            for (int rr = 0; rr < 4; rr++) {
                int row = row0 + rr;
                float v = acc[fm][fn][rr] + bv;
                if constexpr (LAYER == 1) {
                    v = v > 0.f ? v : 0.f;
                } else {
                    v *= lw[row];
                }
                Cout[(size_t)row * HID + col] = (_Float16)v;
            }
        }
    }
}

// ---------------- combine the two weighted expert rows per token ----------------
__global__ __launch_bounds__(256) void k_combine(const _Float16* __restrict__ yb,
                                                 const int* __restrict__ tslot,
                                                 float* __restrict__ out) {
    int t = blockIdx.x;
    int s0 = tslot[2 * t], s1 = tslot[2 * t + 1];
    int c = threadIdx.x * 8;
    half8 y0 = *(const half8*)&yb[(size_t)s0 * HID + c];
    half8 y1 = *(const half8*)&yb[(size_t)s1 * HID + c];
    float* op = out + (size_t)t * HID + c;
    float4 o;
    o.x = (float)y0[0] + (float)y1[0];
    o.y = (float)y0[1] + (float)y1[1];
    o.z = (float)y0[2] + (float)y1[2];
    o.w = (float)y0[3] + (float)y1[3];
    *(float4*)(op) = o;
    o.x = (float)y0[4] + (float)y1[4];
    o.y = (float)y0[5] + (float)y1[5];
    o.z = (float)y0[6] + (float)y1[6];
    o.w = (float)y0[7] + (float)y1[7];
    *(float4*)(op + 4) = o;
}

extern "C" void kernel_launch(void* const* d_in, const int* in_sizes, int n_in,
                              void* d_out, int out_size, void* d_ws, size_t ws_size,
                              hipStream_t stream) {
    const float* x  = (const float*)d_in[0];
    const float* Wg = (const float*)d_in[1];
    const float* bg = (const float*)d_in[2];
    const float* W1 = (const float*)d_in[3];
    const float* b1 = (const float*)d_in[4];
    const float* W2 = (const float*)d_in[5];
    const float* b2 = (const float*)d_in[6];
    float* out = (float*)d_out;

    // ws layout (yb aliases xh+w1t, both dead by gemm2)
    char* ws = (char*)d_ws;
    _Float16* xh  = (_Float16*)(ws);
    _Float16* yb  = (_Float16*)(ws);                        // alias: safe, see order
    _Float16* w1t = (_Float16*)(ws + 33554432ULL);
    _Float16* w2t = (_Float16*)(ws + 100663296ULL);
    _Float16* hb  = (_Float16*)(ws + 167772160ULL);
    char* rt = ws + 167772160ULL + (size_t)ARENA * HID * 2; // 243,269,632
    int*   counts = (int*)(rt);              // 8
    int*   poff   = (int*)(rt + 64);         // 9
    int*   cj     = (int*)(rt + 128);        // 9
    int*   te     = (int*)(rt + 192);        // 16384 ints
    float* tw     = (float*)(rt + 192 + 65536);
    int*   tslot  = (int*)(rt + 192 + 131072);
    int*   ltok   = (int*)(rt + 192 + 196608);              // ARENA ints
    float* lw     = (float*)(rt + 192 + 196608 + 73728);    // ARENA floats

    hipMemsetAsync(rt, 0, 64, stream);                   // counts
    hipMemsetAsync(ltok, 0, (size_t)ARENA * 8, stream);  // ltok + lw pads = 0
    k_prep_gate<<<dim3(8704), 256, 0, stream>>>(W1, w1t, x, Wg, bg, xh, te, tw, counts);
    k_route<<<1, 256, 0, stream>>>(counts, poff, cj, te, tw, ltok, lw, tslot);
    k_gemm<1><<<dim3(NJOBS + 8192), 512, 0, stream>>>(xh, w1t, b1, cj, poff, ltok,
                                                      nullptr, W2, w2t, hb);
    k_gemm<2><<<dim3(NJOBS), 512, 0, stream>>>(hb, w2t, b2, cj, poff, ltok, lw,
                                               nullptr, nullptr, yb);
    k_combine<<<8192, 256, 0, stream>>>(yb, tslot, out);
}

// Round 16
// 432.928 us; speedup vs baseline: 1.4061x; 1.0704x over previous
//
#include <hip/hip_runtime.h>
#include <hip/hip_bf16.h>
#include <cstdint>
#include <cstddef>

#define N_TOK 8192
#define DIM   2048
#define HID   2048
#define NE    8
#define ARENA 18432   // >= 16384 + 8*127 padded rows (pad granularity 128)
#define NJOBS 2176    // >= sum_e ceil(cnt_e/128)*16  (<= 136*16)

typedef _Float16 half8  __attribute__((ext_vector_type(8)));
typedef _Float16 half4v __attribute__((ext_vector_type(4)));
typedef float    floatx4 __attribute__((ext_vector_type(4)));

#define BARR  __builtin_amdgcn_s_barrier()
#define LGKM0 asm volatile("s_waitcnt lgkmcnt(0)" ::: "memory")
#define VMC0  asm volatile("s_waitcnt vmcnt(0)" ::: "memory")

__device__ inline void gload_lds16(const void* g, void* l) {
    __builtin_amdgcn_global_load_lds(
        (const __attribute__((address_space(1))) unsigned int*)g,
        (__attribute__((address_space(3))) unsigned int*)l, 16, 0, 0);
}

__device__ __forceinline__ floatx4 MF(half8 a, half8 b, floatx4 c) {
    return __builtin_amdgcn_mfma_f32_16x16x32_f16(a, b, c, 0, 0, 0);
}

// ========== merged prep(W1 transpose->fp16) + gate (logits/top2/x->fp16) ==========
// blocks [0,8192): transpose W1 [E][R][C] fp32 -> [E][C][R] fp16
// blocks [8192,8704): gate. prep is HBM-bound, gate latency-bound -> overlap.
// (W2's transpose rides inside the gemm1 dispatch - it is not a gemm1 dep.)
__global__ __launch_bounds__(256) void k_prep_gate(
        const float* __restrict__ W1, _Float16* __restrict__ w1t,
        const float* __restrict__ x, const float* __restrict__ Wg,
        const float* __restrict__ bg, _Float16* __restrict__ xh,
        int* __restrict__ te, float* __restrict__ tw, int* __restrict__ counts) {
    __shared__ __align__(16) char smem[65568];
    int b = blockIdx.x;
    if (b < 8192) {
        // ---------------- prep W1 ----------------
        float (*tile)[65] = (float (*)[65])smem;
        int e = b >> 10, rem = b & 1023;
        int r0 = (rem >> 5) * 64, c0 = (rem & 31) * 64;
        int tc = threadIdx.x & 63, tr = threadIdx.x >> 6;   // tr 0..3
        const float* ip = W1 + ((size_t)e * 2048 + r0) * 2048 + c0;
#pragma unroll
        for (int i = 0; i < 16; i++)
            tile[tr + i * 4][tc] = ip[(size_t)(tr + i * 4) * 2048 + tc];
        __syncthreads();
        _Float16* op = w1t + ((size_t)e * 2048 + c0) * 2048 + r0;
#pragma unroll
        for (int i = 0; i < 16; i++) {
            int cc = tr + i * 4;
            op[(size_t)cc * 2048 + tc] = (_Float16)tile[tc][cc];
        }
        return;
    }
    // ---------------- gate ----------------
    int bid = b - 8192;
    float* wgs = (float*)smem;             // 64 KB transposed [e][d]
    int* lcnt  = (int*)(smem + 65536);
    if (threadIdx.x < NE) lcnt[threadIdx.x] = 0;
    for (int i = threadIdx.x; i < NE * DIM; i += 256)
        wgs[(i & 7) * DIM + (i >> 3)] = Wg[i];
    __syncthreads();
    int wv = threadIdx.x >> 6, l = threadIdx.x & 63;
#pragma unroll 1
    for (int it = 0; it < 4; ++it) {
        int t = bid * 16 + wv * 4 + it;
        const float* xr = x + (size_t)t * DIM;
        double acc[NE] = {0, 0, 0, 0, 0, 0, 0, 0};
#pragma unroll 2
        for (int i = 0; i < 8; i++) {
            int d0 = i * 256 + l * 4;
            float4 xv = *(const float4*)(xr + d0);
            half4v hv;
            hv[0] = (_Float16)xv.x; hv[1] = (_Float16)xv.y;
            hv[2] = (_Float16)xv.z; hv[3] = (_Float16)xv.w;
            *(half4v*)(xh + (size_t)t * DIM + d0) = hv;
#pragma unroll
            for (int e = 0; e < NE; e++) {
                float4 w4 = *(const float4*)(wgs + e * DIM + d0);
                acc[e] += (double)xv.x * w4.x + (double)xv.y * w4.y +
                          (double)xv.z * w4.z + (double)xv.w * w4.w;
            }
        }
#pragma unroll
        for (int e = 0; e < NE; e++) {
            double v = acc[e];
            v += __shfl_xor(v, 32, 64); v += __shfl_xor(v, 16, 64);
            v += __shfl_xor(v, 8, 64);  v += __shfl_xor(v, 4, 64);
            v += __shfl_xor(v, 2, 64);  v += __shfl_xor(v, 1, 64);
            acc[e] = v;
        }
        if (l == 0) {
            double best0 = -1e300, best1 = -1e300; int i0 = 0, i1 = 0;
#pragma unroll
            for (int e = 0; e < NE; e++) {
                double lg = acc[e] + (double)bg[e];
                if (lg > best0) { best1 = best0; i1 = i0; best0 = lg; i0 = e; }
                else if (lg > best1) { best1 = lg; i1 = e; }
            }
            float d  = expf((float)(best1 - best0));
            float w0 = 1.f / (1.f + d), w1 = d / (1.f + d);
            te[2 * t] = i0; te[2 * t + 1] = i1;
            tw[2 * t] = w0; tw[2 * t + 1] = w1;
            atomicAdd(&lcnt[i0], 1);
            atomicAdd(&lcnt[i1], 1);
        }
    }
    __syncthreads();
    if (threadIdx.x < NE) atomicAdd(&counts[threadIdx.x], lcnt[threadIdx.x]);
}

// ---------------- route: scan (128-padded arena offsets + job table) + scatter ----------------
__global__ __launch_bounds__(256) void k_route(const int* __restrict__ counts,
                                               int* __restrict__ poff, int* __restrict__ cj,
                                               const int* __restrict__ te,
                                               const float* __restrict__ tw,
                                               int* __restrict__ ltok, float* __restrict__ lw,
                                               int* __restrict__ tslot) {
    __shared__ int spoff[NE], sfill[NE];
    if (threadIdx.x == 0) {
        int a = 0, jc = 0;
        for (int e = 0; e < NE; e++) {
            poff[e] = a; cj[e] = jc; spoff[e] = a;
            int mb = (counts[e] + 127) >> 7;
            a  += mb << 7;
            jc += mb * 16;       // 16 n-tiles of 128
        }
        poff[NE] = a; cj[NE] = jc;
    }
    if (threadIdx.x < NE) sfill[threadIdx.x] = 0;
    __syncthreads();
#pragma unroll 1
    for (int t = threadIdx.x; t < N_TOK; t += 256) {
#pragma unroll
        for (int k = 0; k < 2; k++) {
            int e = te[2 * t + k];
            int p = atomicAdd(&sfill[e], 1);
            int idx = spoff[e] + p;
            ltok[idx] = t; lw[idx] = tw[2 * t + k]; tslot[2 * t + k] = idx;
        }
    }
}

// ====== m97-style GEMM: BM=BN=128, BK=64, single-buffer, 4 blocks/CU ======
// 256 thr = 4 waves (2m x 2n); wave tile 64x64; acc[4][4] of 16x16x32_f16.
// LDS 32 KB single buffer; __launch_bounds__(256,4): 4 waves/SIMD and 32KB
// LDS -> 4 blocks/CU resident (vs 2 at the 256x128 tile).  Deeper inter-block
// overlap fills the drain/barrier stalls (m114, m97's 912 TF geometry), and
// the 4x smaller job quantum cuts the dispatch straggler tail.
// Proven-kept: arena padding (no row guards), nb-inner job order (j, j+16
// share B panel on one XCD), XOR swizzle both-sides (rule 21), W2 transpose
// riding in the gemm1 dispatch.

template<int LAYER>
__global__ __launch_bounds__(256, 4) void k_gemm(const _Float16* __restrict__ Ain,
                                                 const _Float16* __restrict__ Bt,
                                                 const float* __restrict__ bias,
                                                 const int* __restrict__ cj,
                                                 const int* __restrict__ poff,
                                                 const int* __restrict__ ltok,
                                                 const float* __restrict__ lw,
                                                 const float* __restrict__ W2in,
                                                 _Float16* __restrict__ w2tO,
                                                 _Float16* __restrict__ Cout) {
    __shared__ __align__(16) char smem[32768];
    int j = blockIdx.x;

    if constexpr (LAYER == 1) {
        if (j >= NJOBS) {
            // ---------------- W2 transpose (256 threads) ----------------
            float (*tile)[65] = (float (*)[65])smem;      // 16.6 KB of the 32
            int b2 = j - NJOBS;
            int e = b2 >> 10, rem = b2 & 1023;
            int r0 = (rem >> 5) * 64, c0 = (rem & 31) * 64;
            int tc = threadIdx.x & 63, tr = threadIdx.x >> 6;   // tr 0..3
            const float* ip = W2in + ((size_t)e * 2048 + r0) * 2048 + c0;
#pragma unroll
            for (int i = 0; i < 16; i++)
                tile[tr + i * 4][tc] = ip[(size_t)(tr + i * 4) * 2048 + tc];
            __syncthreads();
            _Float16* op = w2tO + ((size_t)e * 2048 + c0) * 2048 + r0;
#pragma unroll
            for (int i = 0; i < 16; i++) {
                int cc = tr + i * 4;
                op[(size_t)cc * 2048 + tc] = (_Float16)tile[tc][cc];
            }
            return;
        }
    }

    _Float16* As = (_Float16*)smem;             // 128x64 halves = 16 KB
    _Float16* Bs = (_Float16*)(smem + 16384);   // 128x64 halves = 16 KB

    if (j >= cj[NE]) return;
    int e = 0;
#pragma unroll
    for (int k = 0; k < NE - 1; k++) e += (j >= cj[k + 1]);
    int r  = j - cj[e];
    int m0 = poff[e] + (r >> 4) * 128;   // arena row base
    int n0 = (r & 15) * 128;

    int tid = threadIdx.x;
    int l = tid & 63;
    int wid = tid >> 6;
    int wm = wid >> 1, wn = wid & 1;     // 2m x 2n
    int lr = l & 15, lk = l >> 4;
    int rA = (wm * 64 + lr) * 64;
    int rB = (wn * 64 + lr) * 64;

    int sd = tid * 8;                    // staging dest (lane-linear, m104-safe)
    size_t koff = (size_t)(((tid & 7) ^ ((tid >> 3) & 7)) * 8);  // pre-swizzled

    // each round of 256 thr covers 32 rows (tid>>3) x 8 chunks (tid&7)
    const _Float16* aS[4];
#pragma unroll
    for (int q = 0; q < 4; q++) {
        int ar = m0 + (tid >> 3) + q * 32;
        if constexpr (LAYER == 1) {
            int tok = ltok[ar];
            aS[q] = Ain + (size_t)tok * DIM + koff;
        } else {
            aS[q] = Ain + (size_t)ar * HID + koff;
        }
    }
    const _Float16* bS[4];
#pragma unroll
    for (int q = 0; q < 4; q++)
        bS[q] = Bt + ((size_t)(e * 2048 + n0 + (tid >> 3) + q * 32)) * 2048 + koff;

    floatx4 acc[4][4];
#pragma unroll
    for (int m = 0; m < 4; m++)
#pragma unroll
        for (int n = 0; n < 4; n++) acc[m][n] = (floatx4){0.f, 0.f, 0.f, 0.f};

    // prologue: stage tile 0 (4 A + 4 B rounds of 2048 halves)
#pragma unroll
    for (int q = 0; q < 4; q++) gload_lds16(aS[q], As + sd + q * 2048);
#pragma unroll
    for (int q = 0; q < 4; q++) gload_lds16(bS[q], Bs + sd + q * 2048);

#pragma unroll 1
    for (int t = 0; t < 32; ++t) {
        VMC0;    // staged tile t landed (co-resident blocks cover this drain)
        BARR;
#pragma unroll
        for (int kk = 0; kk < 2; kk++) {
            int cbo = ((kk * 4 + lk) ^ (lr & 7)) * 8;
            half8 a[4], b[4];
#pragma unroll
            for (int fm = 0; fm < 4; fm++)
                a[fm] = *(const half8*)(As + rA + fm * 1024 + cbo);
#pragma unroll
            for (int fn = 0; fn < 4; fn++)
                b[fn] = *(const half8*)(Bs + rB + fn * 1024 + cbo);
#pragma unroll
            for (int fn = 0; fn < 4; fn++)
#pragma unroll
                for (int fm = 0; fm < 4; fm++)
                    acc[fm][fn] = MF(a[fm], b[fn], acc[fm][fn]);
        }
        LGKM0;   // own reads retired
        BARR;    // all waves done reading -> safe to overwrite buffer
        if (t < 31) {
#pragma unroll
            for (int q = 0; q < 4; q++)
                gload_lds16(aS[q] + (size_t)(t + 1) * 64, As + sd + q * 2048);
#pragma unroll
            for (int q = 0; q < 4; q++)
                gload_lds16(bS[q] + (size_t)(t + 1) * 64, Bs + sd + q * 2048);
        }
    }

    // epilogue (no row guards - arena is padded)
#pragma unroll
    for (int fm = 0; fm < 4; fm++) {
        int row0 = m0 + wm * 64 + fm * 16 + lk * 4;
#pragma unroll
        for (int fn = 0; fn < 4; fn++) {
            int col = n0 + wn * 64 + fn * 16 + lr;
            float bv = bias[e * 2048 + col];
#pragma unroll
            for (int rr = 0; rr < 4; rr++) {
                int row = row0 + rr;
                float v = acc[fm][fn][rr] + bv;
                if constexpr (LAYER == 1) {
                    v = v > 0.f ? v : 0.f;
                } else {
                    v *= lw[row];
                }
                Cout[(size_t)row * HID + col] = (_Float16)v;
            }
        }
    }
}

// ---------------- combine the two weighted expert rows per token ----------------
__global__ __launch_bounds__(256) void k_combine(const _Float16* __restrict__ yb,
                                                 const int* __restrict__ tslot,
                                                 float* __restrict__ out) {
    int t = blockIdx.x;
    int s0 = tslot[2 * t], s1 = tslot[2 * t + 1];
    int c = threadIdx.x * 8;
    half8 y0 = *(const half8*)&yb[(size_t)s0 * HID + c];
    half8 y1 = *(const half8*)&yb[(size_t)s1 * HID + c];
    float* op = out + (size_t)t * HID + c;
    float4 o;
    o.x = (float)y0[0] + (float)y1[0];
    o.y = (float)y0[1] + (float)y1[1];
    o.z = (float)y0[2] + (float)y1[2];
    o.w = (float)y0[3] + (float)y1[3];
    *(float4*)(op) = o;
    o.x = (float)y0[4] + (float)y1[4];
    o.y = (float)y0[5] + (float)y1[5];
    o.z = (float)y0[6] + (float)y1[6];
    o.w = (float)y0[7] + (float)y1[7];
    *(float4*)(op + 4) = o;
}

extern "C" void kernel_launch(void* const* d_in, const int* in_sizes, int n_in,
                              void* d_out, int out_size, void* d_ws, size_t ws_size,
                              hipStream_t stream) {
    const float* x  = (const float*)d_in[0];
    const float* Wg = (const float*)d_in[1];
    const float* bg = (const float*)d_in[2];
    const float* W1 = (const float*)d_in[3];
    const float* b1 = (const float*)d_in[4];
    const float* W2 = (const float*)d_in[5];
    const float* b2 = (const float*)d_in[6];
    float* out = (float*)d_out;

    // ws layout (yb aliases xh+w1t, both dead by gemm2)
    char* ws = (char*)d_ws;
    _Float16* xh  = (_Float16*)(ws);
    _Float16* yb  = (_Float16*)(ws);                        // alias: safe, see order
    _Float16* w1t = (_Float16*)(ws + 33554432ULL);
    _Float16* w2t = (_Float16*)(ws + 100663296ULL);
    _Float16* hb  = (_Float16*)(ws + 167772160ULL);
    char* rt = ws + 167772160ULL + (size_t)ARENA * HID * 2; // 243,269,632
    int*   counts = (int*)(rt);              // 8
    int*   poff   = (int*)(rt + 64);         // 9
    int*   cj     = (int*)(rt + 128);        // 9
    int*   te     = (int*)(rt + 192);        // 16384 ints
    float* tw     = (float*)(rt + 192 + 65536);
    int*   tslot  = (int*)(rt + 192 + 131072);
    int*   ltok   = (int*)(rt + 192 + 196608);              // ARENA ints
    float* lw     = (float*)(rt + 192 + 196608 + 73728);    // ARENA floats

    hipMemsetAsync(rt, 0, 64, stream);                   // counts
    hipMemsetAsync(ltok, 0, (size_t)ARENA * 8, stream);  // ltok + lw pads = 0
    k_prep_gate<<<dim3(8704), 256, 0, stream>>>(W1, w1t, x, Wg, bg, xh, te, tw, counts);
    k_route<<<1, 256, 0, stream>>>(counts, poff, cj, te, tw, ltok, lw, tslot);
    k_gemm<1><<<dim3(NJOBS + 8192), 256, 0, stream>>>(xh, w1t, b1, cj, poff, ltok,
                                                      nullptr, W2, w2t, hb);
    k_gemm<2><<<dim3(NJOBS), 256, 0, stream>>>(hb, w2t, b2, cj, poff, ltok, lw,
                                               nullptr, nullptr, yb);
    k_combine<<<8192, 256, 0, stream>>>(yb, tslot, out);
}

// Round 17
// 431.173 us; speedup vs baseline: 1.4118x; 1.0041x over previous
//
#include <hip/hip_runtime.h>
#include <hip/hip_bf16.h>
#include <cstdint>
#include <cstddef>

#define N_TOK 8192
#define DIM   2048
#define HID   2048
#define NE    8
#define ARENA 18432   // >= 16384 + 8*127 padded rows (pad granularity 128)
#define NJOBS 2176    // >= sum_e ceil(cnt_e/128)*16  (<= 136*16)

typedef _Float16 half8  __attribute__((ext_vector_type(8)));
typedef _Float16 half4v __attribute__((ext_vector_type(4)));
typedef float    floatx4 __attribute__((ext_vector_type(4)));

#define BARR  __builtin_amdgcn_s_barrier()
#define LGKM0 asm volatile("s_waitcnt lgkmcnt(0)" ::: "memory")
#define VMC0  asm volatile("s_waitcnt vmcnt(0)" ::: "memory")

__device__ inline void gload_lds16(const void* g, void* l) {
    __builtin_amdgcn_global_load_lds(
        (const __attribute__((address_space(1))) unsigned int*)g,
        (__attribute__((address_space(3))) unsigned int*)l, 16, 0, 0);
}

__device__ __forceinline__ floatx4 MF(half8 a, half8 b, floatx4 c) {
    return __builtin_amdgcn_mfma_f32_16x16x32_f16(a, b, c, 0, 0, 0);
}

// ========== merged gate (logits/top2/x->fp16) + prep(W1 transpose->fp16) ==========
// blocks [0,512): gate  — scheduled FIRST so the latency-bound gate runs fully
//   under the HBM-bound W1 prep (R16 had gate last -> ~20us serial tail).
// blocks [512,8704): transpose W1 [E][R][C] fp32 -> [E][C][R] fp16.
// (W2's transpose rides inside the gemm1 dispatch - it is not a gemm1 dep.)
__global__ __launch_bounds__(256) void k_prep_gate(
        const float* __restrict__ W1, _Float16* __restrict__ w1t,
        const float* __restrict__ x, const float* __restrict__ Wg,
        const float* __restrict__ bg, _Float16* __restrict__ xh,
        int* __restrict__ te, float* __restrict__ tw, int* __restrict__ counts) {
    __shared__ __align__(16) char smem[65568];
    int b = blockIdx.x;
    if (b >= 512) {
        // ---------------- prep W1 ----------------
        float (*tile)[65] = (float (*)[65])smem;
        int bb = b - 512;
        int e = bb >> 10, rem = bb & 1023;
        int r0 = (rem >> 5) * 64, c0 = (rem & 31) * 64;
        int tc = threadIdx.x & 63, tr = threadIdx.x >> 6;   // tr 0..3
        const float* ip = W1 + ((size_t)e * 2048 + r0) * 2048 + c0;
#pragma unroll
        for (int i = 0; i < 16; i++)
            tile[tr + i * 4][tc] = ip[(size_t)(tr + i * 4) * 2048 + tc];
        __syncthreads();
        _Float16* op = w1t + ((size_t)e * 2048 + c0) * 2048 + r0;
#pragma unroll
        for (int i = 0; i < 16; i++) {
            int cc = tr + i * 4;
            op[(size_t)cc * 2048 + tc] = (_Float16)tile[tc][cc];
        }
        return;
    }
    // ---------------- gate ----------------
    int bid = b;
    float* wgs = (float*)smem;             // 64 KB transposed [e][d]
    int* lcnt  = (int*)(smem + 65536);
    if (threadIdx.x < NE) lcnt[threadIdx.x] = 0;
    for (int i = threadIdx.x; i < NE * DIM; i += 256)
        wgs[(i & 7) * DIM + (i >> 3)] = Wg[i];
    __syncthreads();
    int wv = threadIdx.x >> 6, l = threadIdx.x & 63;
#pragma unroll 1
    for (int it = 0; it < 4; ++it) {
        int t = bid * 16 + wv * 4 + it;
        const float* xr = x + (size_t)t * DIM;
        double acc[NE] = {0, 0, 0, 0, 0, 0, 0, 0};
#pragma unroll 2
        for (int i = 0; i < 8; i++) {
            int d0 = i * 256 + l * 4;
            float4 xv = *(const float4*)(xr + d0);
            half4v hv;
            hv[0] = (_Float16)xv.x; hv[1] = (_Float16)xv.y;
            hv[2] = (_Float16)xv.z; hv[3] = (_Float16)xv.w;
            *(half4v*)(xh + (size_t)t * DIM + d0) = hv;
#pragma unroll
            for (int e = 0; e < NE; e++) {
                float4 w4 = *(const float4*)(wgs + e * DIM + d0);
                acc[e] += (double)xv.x * w4.x + (double)xv.y * w4.y +
                          (double)xv.z * w4.z + (double)xv.w * w4.w;
            }
        }
#pragma unroll
        for (int e = 0; e < NE; e++) {
            double v = acc[e];
            v += __shfl_xor(v, 32, 64); v += __shfl_xor(v, 16, 64);
            v += __shfl_xor(v, 8, 64);  v += __shfl_xor(v, 4, 64);
            v += __shfl_xor(v, 2, 64);  v += __shfl_xor(v, 1, 64);
            acc[e] = v;
        }
        if (l == 0) {
            double best0 = -1e300, best1 = -1e300; int i0 = 0, i1 = 0;
#pragma unroll
            for (int e = 0; e < NE; e++) {
                double lg = acc[e] + (double)bg[e];
                if (lg > best0) { best1 = best0; i1 = i0; best0 = lg; i0 = e; }
                else if (lg > best1) { best1 = lg; i1 = e; }
            }
            float d  = expf((float)(best1 - best0));
            float w0 = 1.f / (1.f + d), w1 = d / (1.f + d);
            te[2 * t] = i0; te[2 * t + 1] = i1;
            tw[2 * t] = w0; tw[2 * t + 1] = w1;
            atomicAdd(&lcnt[i0], 1);
            atomicAdd(&lcnt[i1], 1);
        }
    }
    __syncthreads();
    if (threadIdx.x < NE) atomicAdd(&counts[threadIdx.x], lcnt[threadIdx.x]);
}

// ---------------- route: scan (128-padded arena offsets + job table) + scatter ----------------
__global__ __launch_bounds__(256) void k_route(const int* __restrict__ counts,
                                               int* __restrict__ poff, int* __restrict__ cj,
                                               const int* __restrict__ te,
                                               const float* __restrict__ tw,
                                               int* __restrict__ ltok, float* __restrict__ lw,
                                               int* __restrict__ tslot) {
    __shared__ int spoff[NE], sfill[NE];
    if (threadIdx.x == 0) {
        int a = 0, jc = 0;
        for (int e = 0; e < NE; e++) {
            poff[e] = a; cj[e] = jc; spoff[e] = a;
            int mb = (counts[e] + 127) >> 7;
            a  += mb << 7;
            jc += mb * 16;       // 16 n-tiles of 128
        }
        poff[NE] = a; cj[NE] = jc;
    }
    if (threadIdx.x < NE) sfill[threadIdx.x] = 0;
    __syncthreads();
#pragma unroll 1
    for (int t = threadIdx.x; t < N_TOK; t += 256) {
#pragma unroll
        for (int k = 0; k < 2; k++) {
            int e = te[2 * t + k];
            int p = atomicAdd(&sfill[e], 1);
            int idx = spoff[e] + p;
            ltok[idx] = t; lw[idx] = tw[2 * t + k]; tslot[2 * t + k] = idx;
        }
    }
}

// ====== m97-style GEMM: BM=BN=128, BK=64, single-buffer, 4 blocks/CU ======
// 256 thr = 4 waves (2m x 2n); wave tile 64x64; acc[4][4] of 16x16x32_f16.
// LDS 32 KB single buffer; __launch_bounds__(256,4): 4 blocks/CU resident.
// Co-resident blocks fill each other's drain/barrier stalls (m114; m97's
// proven geometry -> MfmaUtil ~38%, the documented plateau of this structure).
// Proven-kept: arena padding (no row guards), nb-inner job order, XOR swizzle
// both-sides (rule 21), W2 transpose riding in the gemm1 dispatch tail.

template<int LAYER>
__global__ __launch_bounds__(256, 4) void k_gemm(const _Float16* __restrict__ Ain,
                                                 const _Float16* __restrict__ Bt,
                                                 const float* __restrict__ bias,
                                                 const int* __restrict__ cj,
                                                 const int* __restrict__ poff,
                                                 const int* __restrict__ ltok,
                                                 const float* __restrict__ lw,
                                                 const float* __restrict__ W2in,
                                                 _Float16* __restrict__ w2tO,
                                                 _Float16* __restrict__ Cout) {
    __shared__ __align__(16) char smem[32768];
    int j = blockIdx.x;

    if constexpr (LAYER == 1) {
        if (j >= NJOBS) {
            // ---------------- W2 transpose (256 threads) ----------------
            float (*tile)[65] = (float (*)[65])smem;      // 16.6 KB of the 32
            int b2 = j - NJOBS;
            int e = b2 >> 10, rem = b2 & 1023;
            int r0 = (rem >> 5) * 64, c0 = (rem & 31) * 64;
            int tc = threadIdx.x & 63, tr = threadIdx.x >> 6;   // tr 0..3
            const float* ip = W2in + ((size_t)e * 2048 + r0) * 2048 + c0;
#pragma unroll
            for (int i = 0; i < 16; i++)
                tile[tr + i * 4][tc] = ip[(size_t)(tr + i * 4) * 2048 + tc];
            __syncthreads();
            _Float16* op = w2tO + ((size_t)e * 2048 + c0) * 2048 + r0;
#pragma unroll
            for (int i = 0; i < 16; i++) {
                int cc = tr + i * 4;
                op[(size_t)cc * 2048 + tc] = (_Float16)tile[tc][cc];
            }
            return;
        }
    }

    _Float16* As = (_Float16*)smem;             // 128x64 halves = 16 KB
    _Float16* Bs = (_Float16*)(smem + 16384);   // 128x64 halves = 16 KB

    if (j >= cj[NE]) return;
    int e = 0;
#pragma unroll
    for (int k = 0; k < NE - 1; k++) e += (j >= cj[k + 1]);
    int r  = j - cj[e];
    int m0 = poff[e] + (r >> 4) * 128;   // arena row base
    int n0 = (r & 15) * 128;

    int tid = threadIdx.x;
    int l = tid & 63;
    int wid = tid >> 6;
    int wm = wid >> 1, wn = wid & 1;     // 2m x 2n
    int lr = l & 15, lk = l >> 4;
    int rA = (wm * 64 + lr) * 64;
    int rB = (wn * 64 + lr) * 64;

    int sd = tid * 8;                    // staging dest (lane-linear, m104-safe)
    size_t koff = (size_t)(((tid & 7) ^ ((tid >> 3) & 7)) * 8);  // pre-swizzled

    // each round of 256 thr covers 32 rows (tid>>3) x 8 chunks (tid&7)
    const _Float16* aS[4];
#pragma unroll
    for (int q = 0; q < 4; q++) {
        int ar = m0 + (tid >> 3) + q * 32;
        if constexpr (LAYER == 1) {
            int tok = ltok[ar];
            aS[q] = Ain + (size_t)tok * DIM + koff;
        } else {
            aS[q] = Ain + (size_t)ar * HID + koff;
        }
    }
    const _Float16* bS[4];
#pragma unroll
    for (int q = 0; q < 4; q++)
        bS[q] = Bt + ((size_t)(e * 2048 + n0 + (tid >> 3) + q * 32)) * 2048 + koff;

    floatx4 acc[4][4];
#pragma unroll
    for (int m = 0; m < 4; m++)
#pragma unroll
        for (int n = 0; n < 4; n++) acc[m][n] = (floatx4){0.f, 0.f, 0.f, 0.f};

    // prologue: stage tile 0 (4 A + 4 B rounds of 2048 halves)
#pragma unroll
    for (int q = 0; q < 4; q++) gload_lds16(aS[q], As + sd + q * 2048);
#pragma unroll
    for (int q = 0; q < 4; q++) gload_lds16(bS[q], Bs + sd + q * 2048);

#pragma unroll 1
    for (int t = 0; t < 32; ++t) {
        VMC0;    // staged tile t landed (co-resident blocks cover this drain)
        BARR;
#pragma unroll
        for (int kk = 0; kk < 2; kk++) {
            int cbo = ((kk * 4 + lk) ^ (lr & 7)) * 8;
            half8 a[4], b[4];
#pragma unroll
            for (int fm = 0; fm < 4; fm++)
                a[fm] = *(const half8*)(As + rA + fm * 1024 + cbo);
#pragma unroll
            for (int fn = 0; fn < 4; fn++)
                b[fn] = *(const half8*)(Bs + rB + fn * 1024 + cbo);
#pragma unroll
            for (int fn = 0; fn < 4; fn++)
#pragma unroll
                for (int fm = 0; fm < 4; fm++)
                    acc[fm][fn] = MF(a[fm], b[fn], acc[fm][fn]);
        }
        LGKM0;   // own reads retired
        BARR;    // all waves done reading -> safe to overwrite buffer
        if (t < 31) {
#pragma unroll
            for (int q = 0; q < 4; q++)
                gload_lds16(aS[q] + (size_t)(t + 1) * 64, As + sd + q * 2048);
#pragma unroll
            for (int q = 0; q < 4; q++)
                gload_lds16(bS[q] + (size_t)(t + 1) * 64, Bs + sd + q * 2048);
        }
    }

    // epilogue (no row guards - arena is padded)
#pragma unroll
    for (int fm = 0; fm < 4; fm++) {
        int row0 = m0 + wm * 64 + fm * 16 + lk * 4;
#pragma unroll
        for (int fn = 0; fn < 4; fn++) {
            int col = n0 + wn * 64 + fn * 16 + lr;
            float bv = bias[e * 2048 + col];
#pragma unroll
            for (int rr = 0; rr < 4; rr++) {
                int row = row0 + rr;
                float v = acc[fm][fn][rr] + bv;
                if constexpr (LAYER == 1) {
                    v = v > 0.f ? v : 0.f;
                } else {
                    v *= lw[row];
                }
                Cout[(size_t)row * HID + col] = (_Float16)v;
            }
        }
    }
}

// ---------------- combine the two weighted expert rows per token ----------------
__global__ __launch_bounds__(256) void k_combine(const _Float16* __restrict__ yb,
                                                 const int* __restrict__ tslot,
                                                 float* __restrict__ out) {
    int t = blockIdx.x;
    int s0 = tslot[2 * t], s1 = tslot[2 * t + 1];
    int c = threadIdx.x * 8;
    half8 y0 = *(const half8*)&yb[(size_t)s0 * HID + c];
    half8 y1 = *(const half8*)&yb[(size_t)s1 * HID + c];
    float* op = out + (size_t)t * HID + c;
    float4 o;
    o.x = (float)y0[0] + (float)y1[0];
    o.y = (float)y0[1] + (float)y1[1];
    o.z = (float)y0[2] + (float)y1[2];
    o.w = (float)y0[3] + (float)y1[3];
    *(float4*)(op) = o;
    o.x = (float)y0[4] + (float)y1[4];
    o.y = (float)y0[5] + (float)y1[5];
    o.z = (float)y0[6] + (float)y1[6];
    o.w = (float)y0[7] + (float)y1[7];
    *(float4*)(op + 4) = o;
}

extern "C" void kernel_launch(void* const* d_in, const int* in_sizes, int n_in,
                              void* d_out, int out_size, void* d_ws, size_t ws_size,
                              hipStream_t stream) {
    const float* x  = (const float*)d_in[0];
    const float* Wg = (const float*)d_in[1];
    const float* bg = (const float*)d_in[2];
    const float* W1 = (const float*)d_in[3];
    const float* b1 = (const float*)d_in[4];
    const float* W2 = (const float*)d_in[5];
    const float* b2 = (const float*)d_in[6];
    float* out = (float*)d_out;

    // ws layout (yb aliases xh+w1t, both dead by gemm2)
    char* ws = (char*)d_ws;
    _Float16* xh  = (_Float16*)(ws);
    _Float16* yb  = (_Float16*)(ws);                        // alias: safe, see order
    _Float16* w1t = (_Float16*)(ws + 33554432ULL);
    _Float16* w2t = (_Float16*)(ws + 100663296ULL);
    _Float16* hb  = (_Float16*)(ws + 167772160ULL);
    char* rt = ws + 167772160ULL + (size_t)ARENA * HID * 2; // 243,269,632
    int*   counts = (int*)(rt);              // 8
    int*   poff   = (int*)(rt + 64);         // 9
    int*   cj     = (int*)(rt + 128);        // 9
    int*   te     = (int*)(rt + 192);        // 16384 ints
    float* tw     = (float*)(rt + 192 + 65536);
    int*   tslot  = (int*)(rt + 192 + 131072);
    int*   ltok   = (int*)(rt + 192 + 196608);              // ARENA ints
    float* lw     = (float*)(rt + 192 + 196608 + 73728);    // ARENA floats

    hipMemsetAsync(rt, 0, 64, stream);                   // counts
    hipMemsetAsync(ltok, 0, (size_t)ARENA * 8, stream);  // ltok + lw pads = 0
    k_prep_gate<<<dim3(8704), 256, 0, stream>>>(W1, w1t, x, Wg, bg, xh, te, tw, counts);
    k_route<<<1, 256, 0, stream>>>(counts, poff, cj, te, tw, ltok, lw, tslot);
    k_gemm<1><<<dim3(NJOBS + 8192), 256, 0, stream>>>(xh, w1t, b1, cj, poff, ltok,
                                                      nullptr, W2, w2t, hb);
    k_gemm<2><<<dim3(NJOBS), 256, 0, stream>>>(hb, w2t, b2, cj, poff, ltok, lw,
                                               nullptr, nullptr, yb);
    k_combine<<<8192, 256, 0, stream>>>(yb, tslot, out);
}